// Round 2
// baseline (1034.858 us; speedup 1.0000x reference)
//
#include <hip/hip_runtime.h>

// Y[j, b, i] = ((2*x[i,j]+1) >> min(2047-b, 31)) & 1, as float32.
// Y shape [2048, 2048, 64] -> 1 GiB. v = 2x+1 < 4096, so bits are zero for
// shift >= 12, i.e. all columns b < 2036. The kernel is therefore a 1 GiB
// streaming zero-store with a 12-column computed tail.
//
// Structure: one block per j (2048 blocks, 256 threads, 8 blocks/CU = full
// occupancy). Thread t stores quads l = it*256 + t of its j-slab:
//   i4 = l & 15 = t & 15          (constant per thread)
//   b  = l >> 4 = it*16 + (t>>4)  (advances 16 per iteration)
// Iterations 0..126 have b <= 2031 < 2036 -> pure zero stores, no branch,
// no ALU. Only iteration 127 (b = 2032 + t>>4) computes bits, and only for
// t >= 64. This matches the structure of rocclr's fillBuffer (6.2 TB/s)
// instead of the previous 1M-wave one-store-per-thread launch.
//
// NOTE: __builtin_nontemporal_store needs a native vector type, not
// HIP_vector_type<float,4> — use an ext_vector_type alias (same 16B layout).

#define EMB 2048
#define BATCH 64
#define QUADS_PER_J (EMB * BATCH / 4)   // 32768 float4 per j-slab
#define NITER (QUADS_PER_J / 256)       // 128 stores per thread

typedef float floatx4 __attribute__((ext_vector_type(4)));

__global__ __launch_bounds__(256) void emb_bits_kernel(
    const int* __restrict__ x, floatx4* __restrict__ out) {
    const unsigned int j = blockIdx.x;
    const unsigned int t = threadIdx.x;
    floatx4* __restrict__ base = out + (size_t)j * QUADS_PER_J + t;

    const floatx4 zero = (floatx4)(0.f);

    // 127 pure zero-store iterations: b = it*16 + (t>>4) <= 2031 < 2036.
    #pragma unroll 4
    for (int it = 0; it < NITER - 1; ++it) {
        __builtin_nontemporal_store(zero, base + (size_t)it * 256u);
    }

    // Final iteration: b = 2032 + (t>>4); nonzero only when b >= 2036.
    floatx4 val = zero;
    const unsigned int brow = t >> 4;
    if (brow >= 4u) {
        const int shift = 15 - (int)brow;            // = 2047 - b, in [0, 11]
        const unsigned int i0 = (t & 15u) * 4u;      // batch rows i0..i0+3
        const int v0 = 2 * x[(i0 + 0u) * EMB + j] + 1;
        const int v1 = 2 * x[(i0 + 1u) * EMB + j] + 1;
        const int v2 = 2 * x[(i0 + 2u) * EMB + j] + 1;
        const int v3 = 2 * x[(i0 + 3u) * EMB + j] + 1;
        val.x = (float)((v0 >> shift) & 1);
        val.y = (float)((v1 >> shift) & 1);
        val.z = (float)((v2 >> shift) & 1);
        val.w = (float)((v3 >> shift) & 1);
    }
    __builtin_nontemporal_store(val, base + (size_t)(NITER - 1) * 256u);
}

extern "C" void kernel_launch(void* const* d_in, const int* in_sizes, int n_in,
                              void* d_out, int out_size, void* d_ws, size_t ws_size,
                              hipStream_t stream) {
    const int* x = (const int*)d_in[0];
    floatx4* out = (floatx4*)d_out;
    emb_bits_kernel<<<dim3(EMB), dim3(256), 0, stream>>>(x, out);
}

// Round 3
// 878.850 us; speedup vs baseline: 1.1775x; 1.1775x over previous
//
#include <hip/hip_runtime.h>

// Y[j, b, i] = ((2*x[i,j]+1) >> min(2047-b, 31)) & 1, as float32.
// Y shape [2048, 2048, 64] -> 1 GiB. v = 2x+1 < 4096 (x in [1, 2047]), so
// bits are zero for shift >= 12, i.e. ALL columns b < 2036 are 0.0f.
//
// Strategy: the output is 99.4% zeros. Zero it with hipMemsetAsync — this
// dispatches rocclr's fillBufferAligned, which the profile shows sustaining
// 6.2 TB/s (77% of HBM peak) on this exact box — then overwrite only the
// nonzero tail: for each j, columns b in [2036, 2048) x 64 batch floats =
// one contiguous 3 KB run per j-slab (6.3 MB total, ~10 us).
//
// Tail indexing (quad units, 1 quad = float4 = 4 batch elems):
//   j-slab = 2048*64/4 = 32768 quads; tail starts at b=2036 -> quad 32576.
//   thread t in [0,192): brow = t>>4 (b = 2036+brow), i4 = t&15.
//   shift = 2047 - b = 11 - brow in [0, 11].

#define EMB 2048
#define BATCH 64

typedef float floatx4 __attribute__((ext_vector_type(4)));

__global__ __launch_bounds__(192) void emb_tail_kernel(
    const int* __restrict__ x, floatx4* __restrict__ out) {
    const unsigned int j = blockIdx.x;
    const unsigned int t = threadIdx.x;          // 0..191 (3 waves)
    const unsigned int brow = t >> 4;            // 0..11
    const int shift = 11 - (int)brow;            // 2047 - (2036+brow)
    const unsigned int i0 = (t & 15u) * 4u;      // batch rows i0..i0+3

    const int v0 = 2 * x[(i0 + 0u) * EMB + j] + 1;
    const int v1 = 2 * x[(i0 + 1u) * EMB + j] + 1;
    const int v2 = 2 * x[(i0 + 2u) * EMB + j] + 1;
    const int v3 = 2 * x[(i0 + 3u) * EMB + j] + 1;

    floatx4 val;
    val.x = (float)((v0 >> shift) & 1);
    val.y = (float)((v1 >> shift) & 1);
    val.z = (float)((v2 >> shift) & 1);
    val.w = (float)((v3 >> shift) & 1);

    out[(size_t)j * 32768u + 32576u + t] = val;
}

extern "C" void kernel_launch(void* const* d_in, const int* in_sizes, int n_in,
                              void* d_out, int out_size, void* d_ws, size_t ws_size,
                              hipStream_t stream) {
    const int* x = (const int*)d_in[0];
    floatx4* out = (floatx4*)d_out;
    // Bulk zeros at fillBufferAligned's demonstrated 6.2 TB/s.
    hipMemsetAsync(d_out, 0, (size_t)out_size, stream);
    // Nonzero tail: 2048 blocks x 192 threads, one 16B store each.
    emb_tail_kernel<<<dim3(EMB), dim3(192), 0, stream>>>(x, out);
}